// Round 11
// baseline (3591.187 us; speedup 1.0000x reference)
//
#include <hip/hip_runtime.h>
#include <hip/hip_fp16.h>
#include <stdint.h>

#define NDIST 65536
#define NSTEPS 250

#if __has_builtin(__builtin_rotateleft32)
#define ROTL(x, r) __builtin_rotateleft32((x), (r))
#else
#define ROTL(x, r) (((x) << (r)) | ((x) >> (32 - (r))))
#endif

// Threefry-2x32, 20 rounds, exactly as jax/_src/prng.py.
#define TF_ROUND(r) { x0 += x1; x1 = ROTL(x1, r); x1 ^= x0; }

__device__ __forceinline__ uint2 threefry2x32(uint32_t ks0, uint32_t ks1, uint32_t ks2,
                                              uint32_t x0, uint32_t x1) {
  x0 += ks0; x1 += ks1;
  TF_ROUND(13) TF_ROUND(15) TF_ROUND(26) TF_ROUND(6)
  x0 += ks1; x1 += ks2 + 1u;
  TF_ROUND(17) TF_ROUND(29) TF_ROUND(16) TF_ROUND(24)
  x0 += ks2; x1 += ks0 + 2u;
  TF_ROUND(13) TF_ROUND(15) TF_ROUND(26) TF_ROUND(6)
  x0 += ks0; x1 += ks1 + 3u;
  TF_ROUND(17) TF_ROUND(29) TF_ROUND(16) TF_ROUND(24)
  x0 += ks1; x1 += ks2 + 4u;
  TF_ROUND(13) TF_ROUND(15) TF_ROUND(26) TF_ROUND(6)
  x0 += ks2; x1 += ks0 + 5u;
  return make_uint2(x0, x1);
}

// y-only variant: skips the dead final x0 += ks2 (we consume only .y).
__device__ __forceinline__ uint32_t threefry2x32_y(uint32_t ks0, uint32_t ks1, uint32_t ks2,
                                                   uint32_t x0, uint32_t x1) {
  x0 += ks0; x1 += ks1;
  TF_ROUND(13) TF_ROUND(15) TF_ROUND(26) TF_ROUND(6)
  x0 += ks1; x1 += ks2 + 1u;
  TF_ROUND(17) TF_ROUND(29) TF_ROUND(16) TF_ROUND(24)
  x0 += ks2; x1 += ks0 + 2u;
  TF_ROUND(13) TF_ROUND(15) TF_ROUND(26) TF_ROUND(6)
  x0 += ks0; x1 += ks1 + 3u;
  TF_ROUND(17) TF_ROUND(29) TF_ROUND(16) TF_ROUND(24)
  x0 += ks1; x1 += ks2 + 4u;
  TF_ROUND(13) TF_ROUND(15) TF_ROUND(26) TF_ROUND(6)
  return x1 + ks0 + 5u;
}

// PRNG stream verified in R5 (partitionable foldlike split, 64-bit draw):
// keys[s] = TF((0,42),(0,s)); k2 = TF(key_s,(0,1)); idx = TF(k2,(0,p)).y & 0xFFFF.

// ---- Setup kernel: 250 step-key pairs -> d_ws (read back via s_load) ----
__global__ void keys_kernel(uint32_t* __restrict__ ks_out) {
  const int tid = threadIdx.x;
  if (tid < NSTEPS) {
    uint2 ks = threefry2x32(0u, 42u, 0x1BD11BDAu ^ 42u, 0u, (uint32_t)tid);
    uint2 k2 = threefry2x32(ks.x, ks.y, ks.x ^ ks.y ^ 0x1BD11BDAu, 0u, 1u);
    ks_out[2 * tid]     = k2.x;
    ks_out[2 * tid + 1] = k2.y;
  }
}

// ---- Fast path v3: cross-step software pipeline ----
#define WGL 1024
#define GL  8   // 8192 elems per WG -> 1024 WGs

__global__ __launch_bounds__(WGL, 1) void fwd_diff_v3(
    const float* __restrict__ x_init,   // [8,1024,1024] fp32
    const float* __restrict__ dist,     // [8,65536] fp32
    const uint32_t* __restrict__ keysg, // [2*250] step keys (uniform)
    float* __restrict__ out) {          // [8,1024,1024] fp32
  extern __shared__ __half tab[];       // 128 KB, Bc pre-folded fp16

  const int tid   = threadIdx.x;
  const int batch = blockIdx.x >> 7;    // 128 WGs per batch
  const int chunk = blockIdx.x & 127;
  const uint32_t base = ((uint32_t)batch << 20) + ((uint32_t)chunk << 13);

  const float Ac = 0.9899494936611665f;  // float32(sqrt(0.98))
  const float Bc = 0.1414213562373095f;  // float32(sqrt(0.02))

  const float4* src = reinterpret_cast<const float4*>(dist + (size_t)batch * NDIST);
  for (int i = tid; i < NDIST / 4; i += WGL) {
    float4 v = src[i];
    ushort4 h;
    h.x = __half_as_ushort(__float2half(Bc * v.x));
    h.y = __half_as_ushort(__float2half(Bc * v.y));
    h.z = __half_as_ushort(__float2half(Bc * v.z));
    h.w = __half_as_ushort(__float2half(Bc * v.w));
    reinterpret_cast<ushort4*>(tab)[i] = h;
  }
  __syncthreads();

  uint32_t p[GL];
  float acc[GL];
#pragma unroll
  for (int j = 0; j < GL; ++j) {
    p[j]   = base + (uint32_t)(j * WGL) + (uint32_t)tid;
    acc[j] = x_init[p[j]];
  }

  // Prologue: indices for step 0 (8 independent chains -> ALU-latency ILP).
  uint32_t idx[GL];
  {
    const uint32_t kx = keysg[0];
    const uint32_t ky = keysg[1];
    const uint32_t kz = kx ^ ky ^ 0x1BD11BDAu;
#pragma unroll
    for (int j = 0; j < GL; ++j)
      idx[j] = threefry2x32_y(kx, ky, kz, 0u, p[j]) & 0xFFFFu;
  }

  // Pipeline: issue gathers for step s; compute chains for step s+1 while the
  // ds_read_u16s are in flight; then consume (lgkm wait amortized over ~600 ALU).
  for (int s = 0; s < NSTEPS; ++s) {
    float sv[GL];
#pragma unroll
    for (int j = 0; j < GL; ++j)
      sv[j] = __half2float(tab[idx[j]]);   // Bc folded into table

    if (s + 1 < NSTEPS) {
      const uint32_t kx = keysg[2 * (s + 1)];
      const uint32_t ky = keysg[2 * (s + 1) + 1];
      const uint32_t kz = kx ^ ky ^ 0x1BD11BDAu;
#pragma unroll
      for (int j = 0; j < GL; ++j)
        idx[j] = threefry2x32_y(kx, ky, kz, 0u, p[j]) & 0xFFFFu;
    }

#pragma unroll
    for (int j = 0; j < GL; ++j)
      acc[j] = fmaf(Ac, acc[j], sv[j]);
  }

#pragma unroll
  for (int j = 0; j < GL; ++j) out[p[j]] = acc[j];
}

// ---- Fallback: proven R9 kernel (keys in LDS), unchanged ----
#define GF9 8

__global__ __launch_bounds__(WGL, 1) void fwd_diff_full(
    const float* __restrict__ x_init,
    const float* __restrict__ dist,
    float* __restrict__ out) {
  extern __shared__ char smem[];
  __half*   tab9 = reinterpret_cast<__half*>(smem);            // 128 KB
  uint32_t* keys = reinterpret_cast<uint32_t*>(smem + 131072); // 2 KB

  const int tid   = threadIdx.x;
  const int batch = blockIdx.x >> 7;
  const int chunk = blockIdx.x & 127;
  const uint32_t base = ((uint32_t)batch << 20) + ((uint32_t)chunk << 13);

  const float Ac = 0.9899494936611665f;
  const float Bc = 0.1414213562373095f;

  const float4* src = reinterpret_cast<const float4*>(dist + (size_t)batch * NDIST);
  for (int i = tid; i < NDIST / 4; i += WGL) {
    float4 v = src[i];
    ushort4 h;
    h.x = __half_as_ushort(__float2half(Bc * v.x));
    h.y = __half_as_ushort(__float2half(Bc * v.y));
    h.z = __half_as_ushort(__float2half(Bc * v.z));
    h.w = __half_as_ushort(__float2half(Bc * v.w));
    reinterpret_cast<ushort4*>(tab9)[i] = h;
  }
  if (tid < NSTEPS) {
    uint2 ks = threefry2x32(0u, 42u, 0x1BD11BDAu ^ 42u, 0u, (uint32_t)tid);
    uint2 k2 = threefry2x32(ks.x, ks.y, ks.x ^ ks.y ^ 0x1BD11BDAu, 0u, 1u);
    keys[2 * tid]     = k2.x;
    keys[2 * tid + 1] = k2.y;
  }
  __syncthreads();

  uint32_t p[GF9];
  float acc[GF9];
#pragma unroll
  for (int j = 0; j < GF9; ++j) {
    p[j]   = base + (uint32_t)(j * WGL) + (uint32_t)tid;
    acc[j] = x_init[p[j]];
  }

  for (int s = 0; s < NSTEPS; ++s) {
    uint32_t kx = keys[2 * s];
    uint32_t ky = keys[2 * s + 1];
    kx = (uint32_t)__builtin_amdgcn_readfirstlane((int)kx);
    ky = (uint32_t)__builtin_amdgcn_readfirstlane((int)ky);
    const uint32_t kz = kx ^ ky ^ 0x1BD11BDAu;
#pragma unroll
    for (int j = 0; j < GF9; ++j) {
      uint2 r = threefry2x32(kx, ky, kz, 0u, p[j]);
      uint32_t idx9 = r.y & 0xFFFFu;
      acc[j] = fmaf(Ac, acc[j], __half2float(tab9[idx9]));
    }
  }

#pragma unroll
  for (int j = 0; j < GF9; ++j) out[p[j]] = acc[j];
}

extern "C" void kernel_launch(void* const* d_in, const int* in_sizes, int n_in,
                              void* d_out, int out_size, void* d_ws, size_t ws_size,
                              hipStream_t stream) {
  const float* x_init = (const float*)d_in[0];
  const float* dist   = (const float*)d_in[1];
  if (n_in >= 2 && in_sizes[0] == 8 * NDIST) {  // defensive swap check
    x_init = (const float*)d_in[1];
    dist   = (const float*)d_in[0];
  }
  float* out = (float*)d_out;
  uint32_t* keysg = (uint32_t*)d_ws;   // 2 KB of scratch

  const int smem_v3 = 131072;          // table only

  hipError_t st = hipFuncSetAttribute(
      reinterpret_cast<const void*>(fwd_diff_v3),
      hipFuncAttributeMaxDynamicSharedMemorySize, smem_v3);
  int max_blocks = 0;
  if (st == hipSuccess) {
    st = hipOccupancyMaxActiveBlocksPerMultiprocessor(
        &max_blocks, reinterpret_cast<const void*>(fwd_diff_v3), WGL, smem_v3);
  }

  if (st == hipSuccess && max_blocks >= 1 && ws_size >= 2 * NSTEPS * sizeof(uint32_t)) {
    keys_kernel<<<dim3(1), dim3(256), 0, stream>>>(keysg);
    // 8 batches x 128 chunks; 8192 elems/WG (1024 thr x G=8).
    fwd_diff_v3<<<dim3(1024), dim3(WGL), smem_v3, stream>>>(x_init, dist, keysg, out);
  } else {
    const int smem_v1 = 131072 + 2048;
    (void)hipFuncSetAttribute(reinterpret_cast<const void*>(fwd_diff_full),
                              hipFuncAttributeMaxDynamicSharedMemorySize, smem_v1);
    // Proven R9 path: 3.56 ms.
    fwd_diff_full<<<dim3(1024), dim3(WGL), smem_v1, stream>>>(x_init, dist, out);
  }
}